// Round 6
// baseline (521.582 us; speedup 1.0000x reference)
//
#include <hip/hip_runtime.h>
#include <hip/hip_bf16.h>

#define D_IN 512
#define NEXP 32
#define HID 16
#define NT 34            // 544 cols / 16
#define KSTEPS 16        // 512 / 32
#define BM 64            // rows per block
#define NWAVE 6
#define BATCH 262144
#define GSTR 66          // gate-LDS row stride

typedef __attribute__((ext_vector_type(8))) short bfrag;   // 8 x bf16
typedef __attribute__((ext_vector_type(4))) float f32x4;

__device__ inline ushort f2bf(float f) {
  uint32_t u = __float_as_uint(f);
  u += 0x7fffu + ((u >> 16) & 1u);      // RNE, finite inputs
  return (ushort)(u >> 16);
}

__device__ inline uint cvtpk(float lo, float hi) {
  uint r;
  asm("v_cvt_pk_bf16_f32 %0, %1, %2" : "=v"(r) : "v"(lo), "v"(hi));
  return r;
}

// tanh-form GELU, exp-based
__device__ inline float gelu_t(float v) {
  float t = 0.7978845608028654f * fmaf(0.044715f * v * v, v, v);
  t = fminf(fmaxf(t, -9.f), 9.f);
  float e = __expf(-2.f * t);
  float th = (1.f - e) * __builtin_amdgcn_rcpf(1.f + e);
  return 0.5f * v * (1.f + th);
}

__device__ inline void gload_lds16(const ushort* g, ushort* l) {
  __builtin_amdgcn_global_load_lds(
      (const __attribute__((address_space(1))) void*)g,
      (__attribute__((address_space(3))) void*)l, 16, 0, 0);
}

// ---- Pre-pack Wcat[512,544] into bf16 MFMA fragment order:
// P[ks][t][lane][j] = Wcat[k=ks*32+(l>>4)*8+j][n=t*16+(l&15)]
__global__ void prepack_kernel(const float* __restrict__ Wg,
                               const float* __restrict__ W1,
                               ushort* __restrict__ P) {
  int tid = blockIdx.x * 256 + threadIdx.x;
  const int total = KSTEPS * NT * 64;
  if (tid >= total) return;
  int l  = tid & 63;
  int t  = (tid >> 6) % NT;
  int ks = tid / (NT * 64);
  int n  = t * 16 + (l & 15);
  int kb = ks * 32 + (l >> 4) * 8;
  __align__(16) ushort v[8];
#pragma unroll
  for (int j = 0; j < 8; ++j) {
    int k = kb + j;
    float w;
    if (n < NEXP) {
      w = Wg[n * D_IN + k];
    } else {
      int e = (n - 32) >> 4, h = (n - 32) & 15;
      w = W1[(e * D_IN + k) * HID + h];
    }
    v[j] = f2bf(w);
  }
  *reinterpret_cast<int4*>(P + (size_t)tid * 8) = *reinterpret_cast<const int4*>(v);
}

// ---- Main fused kernel: 384 thr = 6 waves, BM=64 rows. Each wave: 64 rows x
// 6 col-tiles (starts 0,6,12,17,23,28; tiles 17,28 duplicated). acc = 96 regs.
// A(x) -> bf16 LDS (4KB dbuf, shared); B single-buffered LDS via global_load_lds.
// acc = mfma(Wfrag, xfrag) -> C^T: lane&15 = batch row, (l>>4)*4+r = col-in-tile.
__global__ __launch_bounds__(384, 3)
void moe_kernel(const float* __restrict__ x, const ushort* __restrict__ P,
                const float* __restrict__ b1, const float* __restrict__ W2,
                const float* __restrict__ b2, float* __restrict__ out) {
  __shared__ __align__(16) ushort Blds[NT * 512];      // 34 KB
  __shared__ __align__(16) ushort Abuf[2][BM * 32];    // 2 x 4 KB bf16
  __shared__ float gall[NEXP * GSTR];                  // 8.4 KB
  __shared__ float sl[BM];
  __shared__ float pp[NWAVE][BM];

  const int tid = threadIdx.x;
  const int l = tid & 63;
  const int wid = tid >> 6;
  const int lane16 = l & 15, lg = l >> 4;
  const size_t rowBase = (size_t)blockIdx.x * BM;
  const int sbase = wid * 6 - (wid > 2) - (wid > 4);   // 0,6,12,17,23,28

  f32x4 acc[4][6];
#pragma unroll
  for (int f = 0; f < 4; ++f)
#pragma unroll
    for (int i = 0; i < 6; ++i) acc[f][i] = (f32x4){0.f, 0.f, 0.f, 0.f};

  // A-staging ownership (waves 0-3): float4 slots q and q+256 of 512 per kstep
  const int q = (wid << 6) | l;                  // 0..255 (waves 0-3)
  const int r0 = q >> 3, c0 = q & 7;
  const int r1 = r0 + 32;
  const float* s0 = x + (rowBase + r0) * D_IN + c0 * 4;
  const float* s1 = x + (rowBase + r1) * D_IN + c0 * 4;
  // LDS u16 dst: frag f = r>>4, lane = (c>>1)*16 + (r&15), j0 = (c&1)*4
  const int d0 = ((r0 >> 4) << 9) + ((c0 >> 1) << 7) + ((r0 & 15) << 3) + ((c0 & 1) << 2);
  const int d1 = ((r1 >> 4) << 9) + ((c0 >> 1) << 7) + ((r1 & 15) << 3) + ((c0 & 1) << 2);

  float4 pf0, pf1;

  // ---- prologue: stage B(0); stage A(0); issue A(1)
#pragma unroll
  for (int tg = wid; tg < NT; tg += NWAVE)
    gload_lds16(P + ((size_t)tg * 64 + l) * 8, Blds + tg * 512);
  if (wid < 4) {
    const float4 a0 = *reinterpret_cast<const float4*>(s0);
    const float4 a1 = *reinterpret_cast<const float4*>(s1);
    *reinterpret_cast<uint2*>(&Abuf[0][d0]) = make_uint2(cvtpk(a0.x, a0.y), cvtpk(a0.z, a0.w));
    *reinterpret_cast<uint2*>(&Abuf[0][d1]) = make_uint2(cvtpk(a1.x, a1.y), cvtpk(a1.z, a1.w));
    pf0 = *reinterpret_cast<const float4*>(s0 + 32);
    pf1 = *reinterpret_cast<const float4*>(s1 + 32);
    asm volatile("s_waitcnt vmcnt(2) lgkmcnt(0)" ::: "memory");
  } else {
    asm volatile("s_waitcnt vmcnt(0) lgkmcnt(0)" ::: "memory");
  }
  __builtin_amdgcn_s_barrier();
  __builtin_amdgcn_sched_barrier(0);

#pragma unroll
  for (int ks = 0; ks < KSTEPS; ++ks) {
    const int cur = ks & 1, nxt = cur ^ 1;
    // A fragments for this kstep
    bfrag a[4];
#pragma unroll
    for (int f = 0; f < 4; ++f)
      a[f] = *reinterpret_cast<const bfrag*>(&Abuf[cur][(f << 9) + (l << 3)]);
    // write A(ks+1) into the other buffer (readers gated by next barrier #1)
    if (ks < KSTEPS - 1 && wid < 4) {
      *reinterpret_cast<uint2*>(&Abuf[nxt][d0]) = make_uint2(cvtpk(pf0.x, pf0.y), cvtpk(pf0.z, pf0.w));
      *reinterpret_cast<uint2*>(&Abuf[nxt][d1]) = make_uint2(cvtpk(pf1.x, pf1.y), cvtpk(pf1.z, pf1.w));
    }
    // MFMA over this wave's 6 tiles
#pragma unroll
    for (int i = 0; i < 6; ++i) {
      const bfrag b = *reinterpret_cast<const bfrag*>(&Blds[(sbase + i) * 512 + (l << 3)]);
#pragma unroll
      for (int f = 0; f < 4; ++f)
        acc[f][i] = __builtin_amdgcn_mfma_f32_16x16x32_bf16(b, a[f], acc[f][i], 0, 0, 0);
    }
    if (ks < KSTEPS - 1) {
      // barrier #2: all LDS reads of B(ks)/writes of A(ks+1) complete, then re-stage
      asm volatile("s_waitcnt lgkmcnt(0)" ::: "memory");
      __builtin_amdgcn_sched_barrier(0);
      __builtin_amdgcn_s_barrier();
      __builtin_amdgcn_sched_barrier(0);
#pragma unroll
      for (int tg = wid; tg < NT; tg += NWAVE)
        gload_lds16(P + ((size_t)((ks + 1) * NT + tg) * 64 + l) * 8, Blds + tg * 512);
      if (ks < KSTEPS - 2 && wid < 4) {
        pf0 = *reinterpret_cast<const float4*>(s0 + (ks + 2) * 32);
        pf1 = *reinterpret_cast<const float4*>(s1 + (ks + 2) * 32);
        asm volatile("s_waitcnt vmcnt(2) lgkmcnt(0)" ::: "memory");  // keep A(ks+2) flying
      } else {
        asm volatile("s_waitcnt vmcnt(0) lgkmcnt(0)" ::: "memory");
      }
      __builtin_amdgcn_s_barrier();   // barrier #1: B(ks+1) + A(ks+1) ready
      __builtin_amdgcn_sched_barrier(0);
    }
  }

  // ---- epilogue. C^T: lane16 = row (in 16-group), lg*4+r = col-in-tile.
  if (wid == 0) {
    // gating softmax from tiles 0,1: expert e = i*16 + lg*4 + r
#pragma unroll
    for (int f = 0; f < 4; ++f) {
      const int row = f * 16 + lane16;
      float mx = fmaxf(fmaxf(fmaxf(acc[f][0][0], acc[f][0][1]), fmaxf(acc[f][0][2], acc[f][0][3])),
                       fmaxf(fmaxf(acc[f][1][0], acc[f][1][1]), fmaxf(acc[f][1][2], acc[f][1][3])));
      mx = fmaxf(mx, __shfl_xor(mx, 16));
      mx = fmaxf(mx, __shfl_xor(mx, 32));
      float sum = 0.f;
#pragma unroll
      for (int t = 0; t < 2; ++t)
#pragma unroll
        for (int r = 0; r < 4; ++r) {
          float g = __expf(acc[f][t][r] - mx);
          sum += g;
          gall[(t * 16 + lg * 4 + r) * GSTR + row] = g;
        }
      sum += __shfl_xor(sum, 16);
      sum += __shfl_xor(sum, 32);
      if (lg == 0) sl[row] = sum;
    }
  }
  __syncthreads();

  // experts: tile t = sbase+i holds expert e = t-2 (h = lg*4+r), dedup'd
  float pacc[4] = {0.f, 0.f, 0.f, 0.f};
#pragma unroll
  for (int i = 0; i < 6; ++i) {
    const bool valid = (wid == 0) ? (i >= 2) : (((wid == 3) || (wid == 5)) ? (i > 0) : true);
    if (valid) {
      const int e = sbase + i - 2;
      const float4 b1v = *reinterpret_cast<const float4*>(b1 + e * HID + lg * 4);
      const float4 w2v = *reinterpret_cast<const float4*>(W2 + e * HID + lg * 4);
      const float b2v = b2[e];
#pragma unroll
      for (int f = 0; f < 4; ++f) {
        float p = gelu_t(acc[f][i][0] + b1v.x) * w2v.x;
        p = fmaf(gelu_t(acc[f][i][1] + b1v.y), w2v.y, p);
        p = fmaf(gelu_t(acc[f][i][2] + b1v.z), w2v.z, p);
        p = fmaf(gelu_t(acc[f][i][3] + b1v.w), w2v.w, p);
        p += __shfl_xor(p, 16);
        p += __shfl_xor(p, 32);             // o_e valid in all lanes
        pacc[f] = fmaf(p + b2v, gall[e * GSTR + f * 16 + lane16], pacc[f]);
      }
    }
  }
  if (lg == 0) {
#pragma unroll
    for (int f = 0; f < 4; ++f) pp[wid][f * 16 + lane16] = pacc[f];
  }
  __syncthreads();
  if (tid < BM) {
    float a = pp[0][tid] + pp[1][tid] + pp[2][tid] + pp[3][tid] + pp[4][tid] + pp[5][tid];
    out[rowBase + tid] = a / sl[tid];
  }
}

extern "C" void kernel_launch(void* const* d_in, const int* in_sizes, int n_in,
                              void* d_out, int out_size, void* d_ws, size_t ws_size,
                              hipStream_t stream) {
  const float* x  = (const float*)d_in[0];
  const float* Wg = (const float*)d_in[1];
  const float* W1 = (const float*)d_in[2];
  const float* b1 = (const float*)d_in[3];
  const float* W2 = (const float*)d_in[4];
  const float* b2 = (const float*)d_in[5];
  float* out = (float*)d_out;
  ushort* P = (ushort*)d_ws;   // 16*34*64*8*2 = 557,056 B

  hipLaunchKernelGGL(prepack_kernel, dim3((KSTEPS * NT * 64 + 255) / 256), dim3(256),
                     0, stream, Wg, W1, P);
  hipLaunchKernelGGL(moe_kernel, dim3(BATCH / BM), dim3(384),
                     0, stream, x, P, b1, W2, b2, out);
}

// Round 11
// 332.555 us; speedup vs baseline: 1.5684x; 1.5684x over previous
//
#include <hip/hip_runtime.h>
#include <hip/hip_bf16.h>

#define D_IN 512
#define NEXP 32
#define HID 16
#define NT 34            // 544 cols / 16
#define KSTEPS 16        // 512 / 32
#define BM 128           // rows per block
#define BATCH 262144
#define LDGX 129         // padded row stride for gate-exchange LDS
#define SPW 5            // B-stage ops per wave (8 waves x 5 = 40 >= 34, 6 dups)

typedef __attribute__((ext_vector_type(8))) short bfrag;   // 8 x bf16
typedef __attribute__((ext_vector_type(4))) float f32x4;

__device__ inline ushort f2bf(float f) {
  uint32_t u = __float_as_uint(f);
  u += 0x7fffu + ((u >> 16) & 1u);      // RNE, finite inputs
  return (ushort)(u >> 16);
}

// pack 8 fp32 -> 8 bf16 (RNE) with v_cvt_pk_bf16_f32
__device__ inline bfrag cvt8(const float4 a, const float4 b) {
  union { bfrag v; uint u[4]; } r;
  asm("v_cvt_pk_bf16_f32 %0, %1, %2" : "=v"(r.u[0]) : "v"(a.x), "v"(a.y));
  asm("v_cvt_pk_bf16_f32 %0, %1, %2" : "=v"(r.u[1]) : "v"(a.z), "v"(a.w));
  asm("v_cvt_pk_bf16_f32 %0, %1, %2" : "=v"(r.u[2]) : "v"(b.x), "v"(b.y));
  asm("v_cvt_pk_bf16_f32 %0, %1, %2" : "=v"(r.u[3]) : "v"(b.z), "v"(b.w));
  return r.v;
}

// tanh-form GELU, exp-based
__device__ inline float gelu_t(float v) {
  float t = 0.7978845608028654f * fmaf(0.044715f * v * v, v, v);
  t = fminf(fmaxf(t, -9.f), 9.f);
  float e = __expf(-2.f * t);
  float th = (1.f - e) * __builtin_amdgcn_rcpf(1.f + e);
  return 0.5f * v * (1.f + th);
}

__device__ inline void gload_lds16(const ushort* g, ushort* l) {
  __builtin_amdgcn_global_load_lds(
      (const __attribute__((address_space(1))) void*)g,
      (__attribute__((address_space(3))) void*)l, 16, 0, 0);
}

// ---- Pre-pack Wcat[512,544] into bf16 MFMA fragment order:
// P[ks][t][lane][j] = Wcat[k=ks*32+(l>>4)*8+j][n=t*16+(l&15)]
__global__ void prepack_kernel(const float* __restrict__ Wg,
                               const float* __restrict__ W1,
                               ushort* __restrict__ P) {
  int tid = blockIdx.x * 256 + threadIdx.x;
  const int total = KSTEPS * NT * 64;
  if (tid >= total) return;
  int l  = tid & 63;
  int t  = (tid >> 6) % NT;
  int ks = tid / (NT * 64);
  int n  = t * 16 + (l & 15);
  int kb = ks * 32 + (l >> 4) * 8;
  __align__(16) ushort v[8];
#pragma unroll
  for (int j = 0; j < 8; ++j) {
    int k = kb + j;
    float w;
    if (n < NEXP) {
      w = Wg[n * D_IN + k];
    } else {
      int e = (n - 32) >> 4, h = (n - 32) & 15;
      w = W1[(e * D_IN + k) * HID + h];
    }
    v[j] = f2bf(w);
  }
  *reinterpret_cast<int4*>(P + (size_t)tid * 8) = *reinterpret_cast<const int4*>(v);
}

// ---- Main fused kernel: ROUND-4 STRUCTURE (validated twice) + 2-deep B pipeline.
// 512 thr = 8 waves (wm 0..3 x wn 0..1), BM=128; wave tile 32 rows x 17 tiles,
// acc[2][17]. B triple-buffered LDS: iteration ks computes buf[ks%3], issues
// B(ks+2) into buf[(ks+2)%3]. Every wave stages exactly SPW=5 tiles
// ((wid*5+i)%34; dup tiles get identical data twice - benign). Compile-time
// uniform counts make vmcnt exact: fence vmcnt(9) leaves {A(ks+1)[4],
// B(ks+2)[5]} in flight and drains B(ks+1), which by then has had ~2 ksteps.
// acc = mfma(Wfrag, xfrag) -> C^T: lane&15 = batch row, (l>>4)*4+r = col-in-tile.
__global__ __launch_bounds__(512, 2)
void moe_kernel(const float* __restrict__ x, const ushort* __restrict__ P,
                const float* __restrict__ b1, const float* __restrict__ W2,
                const float* __restrict__ b2, float* __restrict__ out) {
  __shared__ __align__(16) ushort Blds[3][NT * 512];   // 104448 B
  __shared__ float gxl[17 * LDGX];   // gates e=15..31 per row
  __shared__ float p0l[BM];          // wn0 partial sum per row
  __shared__ float sl[BM];           // softmax denom per row

  const int tid = threadIdx.x;
  const int l = tid & 63;
  const int wid = tid >> 6;
  const int wm = wid >> 1, wn = wid & 1;
  const int lane16 = l & 15, lg = l >> 4;
  const size_t rowBase = (size_t)blockIdx.x * BM;

  // this wave's 5 staging tiles (wave-uniform, static-indexed)
  int stg[SPW];
#pragma unroll
  for (int i = 0; i < SPW; ++i) {
    int t = wid * SPW + i;
    stg[i] = (t >= NT) ? (t - NT) : t;
  }

  f32x4 acc[2][17];
#pragma unroll
  for (int f = 0; f < 2; ++f)
#pragma unroll
    for (int t = 0; t < 17; ++t) acc[f][t] = (f32x4){0.f, 0.f, 0.f, 0.f};

  // x fragment: row = rowBase + wm*32 + f*16 + lane16, k = ks*32 + lg*8 + j
  const float* xp0 = x + (rowBase + wm * 32 + lane16) * D_IN + lg * 8;
  const float* xp1 = xp0 + 16 * D_IN;

  float4 abuf[2][4];

  // ---- prologue: issue A(0), then B(0) and B(1); drain A(0)+B(0), keep B(1)
  abuf[0][0] = *reinterpret_cast<const float4*>(xp0);
  abuf[0][1] = *reinterpret_cast<const float4*>(xp0 + 4);
  abuf[0][2] = *reinterpret_cast<const float4*>(xp1);
  abuf[0][3] = *reinterpret_cast<const float4*>(xp1 + 4);
#pragma unroll
  for (int g = 0; g < 2; ++g)
#pragma unroll
    for (int i = 0; i < SPW; ++i)
      gload_lds16(P + ((size_t)(g * NT + stg[i]) * 64 + l) * 8,
                  &Blds[g][stg[i] * 512]);
  asm volatile("s_waitcnt vmcnt(5)" ::: "memory");   // B(0)+A(0) done; B(1) flying
  __builtin_amdgcn_s_barrier();

#pragma unroll
  for (int ks = 0; ks < KSTEPS; ++ks) {
    const int cur = ks & 1, nxt = cur ^ 1;
    const int rb = ks % 3;
    // consume A(ks): compiler's precise wait = vmcnt(5) (B(ks+1) stays in flight)
    const bfrag a0 = cvt8(abuf[cur][0], abuf[cur][1]);
    const bfrag a1 = cvt8(abuf[cur][2], abuf[cur][3]);
    if (ks < KSTEPS - 1) {
      // issue A(ks+1)
      abuf[nxt][0] = *reinterpret_cast<const float4*>(xp0 + (ks + 1) * 32);
      abuf[nxt][1] = *reinterpret_cast<const float4*>(xp0 + (ks + 1) * 32 + 4);
      abuf[nxt][2] = *reinterpret_cast<const float4*>(xp1 + (ks + 1) * 32);
      abuf[nxt][3] = *reinterpret_cast<const float4*>(xp1 + (ks + 1) * 32 + 4);
    }
    if (ks < KSTEPS - 2) {
      // issue B(ks+2) into buf[(ks+2)%3] (2 ksteps of slack to complete)
      const int wb = (ks + 2) % 3;
#pragma unroll
      for (int i = 0; i < SPW; ++i)
        gload_lds16(P + ((size_t)((ks + 2) * NT + stg[i]) * 64 + l) * 8,
                    &Blds[wb][stg[i] * 512]);
    }
#pragma unroll
    for (int t = 0; t < 17; ++t) {
      const bfrag b = *reinterpret_cast<const bfrag*>(
          &Blds[rb][(wn * 17 + t) * 512 + l * 8]);
      acc[0][t] = __builtin_amdgcn_mfma_f32_16x16x32_bf16(b, a0, acc[0][t], 0, 0, 0);
      acc[1][t] = __builtin_amdgcn_mfma_f32_16x16x32_bf16(b, a1, acc[1][t], 0, 0, 0);
    }
    if (ks < KSTEPS - 1) {
      if (ks < KSTEPS - 2)
        asm volatile("s_waitcnt vmcnt(9)" ::: "memory");  // drain B(ks+1); keep A+B(ks+2)
      else
        asm volatile("s_waitcnt vmcnt(4)" ::: "memory");  // drain B(K-1); keep A(K-1)
      __builtin_amdgcn_s_barrier();
    }
  }

  // ---- epilogue (round 4 verbatim): lane16 = row (in 16-group), lg*4+r = col
  const int row0 = wm * 32 + lane16;
  float oreg[17][2];   // wn1: expert outputs, static-indexed

  if (wn == 0) {
    float gh[2][8];    // gate exps: [f][t*4+r], expert e = t*16 + lg*4 + r
    float pac[2] = {0.f, 0.f};
#pragma unroll
    for (int f = 0; f < 2; ++f) {
      const int row = row0 + f * 16;
      float mx = fmaxf(fmaxf(fmaxf(acc[f][0][0], acc[f][0][1]), fmaxf(acc[f][0][2], acc[f][0][3])),
                       fmaxf(fmaxf(acc[f][1][0], acc[f][1][1]), fmaxf(acc[f][1][2], acc[f][1][3])));
      mx = fmaxf(mx, __shfl_xor(mx, 16));
      mx = fmaxf(mx, __shfl_xor(mx, 32));
      float sum = 0.f;
#pragma unroll
      for (int t = 0; t < 2; ++t)
#pragma unroll
        for (int r = 0; r < 4; ++r) {
          float g = __expf(acc[f][t][r] - mx);
          gh[f][t * 4 + r] = g;
          sum += g;
        }
      sum += __shfl_xor(sum, 16);
      sum += __shfl_xor(sum, 32);
      if (lg == 0) sl[row] = sum;
      // export gates for experts 15..31
      if (lg == 3) gxl[row] = gh[f][3];                      // e=15 (t=0,lg=3,r=3)
#pragma unroll
      for (int r = 0; r < 4; ++r)
        gxl[(1 + lg * 4 + r) * LDGX + row] = gh[f][4 + r];   // e=16+lg*4+r
    }
    // experts 0..14 (tiles 2..16): owner-lane accumulate with in-register gates
#pragma unroll
    for (int t = 2; t < 17; ++t) {
      const int e = t - 2;
      const float4 b1v = *reinterpret_cast<const float4*>(b1 + e * HID + lg * 4);
      const float4 w2v = *reinterpret_cast<const float4*>(W2 + e * HID + lg * 4);
      const float b2v = b2[e];
#pragma unroll
      for (int f = 0; f < 2; ++f) {
        float p = gelu_t(acc[f][t][0] + b1v.x) * w2v.x;
        p = fmaf(gelu_t(acc[f][t][1] + b1v.y), w2v.y, p);
        p = fmaf(gelu_t(acc[f][t][2] + b1v.z), w2v.z, p);
        p = fmaf(gelu_t(acc[f][t][3] + b1v.w), w2v.w, p);
        p += __shfl_xor(p, 16);
        p += __shfl_xor(p, 32);                // o_e valid in all lanes
        if (lg == (e >> 2)) pac[f] = fmaf(p + b2v, gh[f][e & 3], pac[f]);
      }
    }
#pragma unroll
    for (int f = 0; f < 2; ++f) {
      float p0 = pac[f];
      p0 += __shfl_xor(p0, 16);
      p0 += __shfl_xor(p0, 32);
      if (lg == 0) p0l[row0 + f * 16] = p0;
    }
  } else {
    // experts 15..31 (tiles 0..16): keep outputs in registers
#pragma unroll
    for (int t = 0; t < 17; ++t) {
      const int e = t + 15;
      const float4 b1v = *reinterpret_cast<const float4*>(b1 + e * HID + lg * 4);
      const float4 w2v = *reinterpret_cast<const float4*>(W2 + e * HID + lg * 4);
      const float b2v = b2[e];
#pragma unroll
      for (int f = 0; f < 2; ++f) {
        float p = gelu_t(acc[f][t][0] + b1v.x) * w2v.x;
        p = fmaf(gelu_t(acc[f][t][1] + b1v.y), w2v.y, p);
        p = fmaf(gelu_t(acc[f][t][2] + b1v.z), w2v.z, p);
        p = fmaf(gelu_t(acc[f][t][3] + b1v.w), w2v.w, p);
        p += __shfl_xor(p, 16);
        p += __shfl_xor(p, 32);
        oreg[t][f] = p + b2v;
      }
    }
  }

  __syncthreads();
  if (wn == 1) {
#pragma unroll
    for (int f = 0; f < 2; ++f) {
      const int row = row0 + f * 16;
      float a = p0l[row];
#pragma unroll
      for (int t = 0; t < 17; ++t)
        a = fmaf(oreg[t][f], gxl[t * LDGX + row], a);
      if (lg == 0) out[rowBase + row] = a / sl[row];
    }
  }
}

extern "C" void kernel_launch(void* const* d_in, const int* in_sizes, int n_in,
                              void* d_out, int out_size, void* d_ws, size_t ws_size,
                              hipStream_t stream) {
  const float* x  = (const float*)d_in[0];
  const float* Wg = (const float*)d_in[1];
  const float* W1 = (const float*)d_in[2];
  const float* b1 = (const float*)d_in[3];
  const float* W2 = (const float*)d_in[4];
  const float* b2 = (const float*)d_in[5];
  float* out = (float*)d_out;
  ushort* P = (ushort*)d_ws;   // 16*34*64*8*2 = 557,056 B

  hipLaunchKernelGGL(prepack_kernel, dim3((KSTEPS * NT * 64 + 255) / 256), dim3(256),
                     0, stream, Wg, W1, P);
  hipLaunchKernelGGL(moe_kernel, dim3(BATCH / BM), dim3(512),
                     0, stream, x, P, b1, W2, b2, out);
}